// Round 1
// baseline (158.392 us; speedup 1.0000x reference)
//
#include <hip/hip_runtime.h>

#define MAX_RULES 512
#define PENALTY_LAMBDA 0.5f

// --- K1: gates = sigmoid(gate_logits), one block of 512 ---
__global__ void gates_kernel(const float* __restrict__ gate_logits,
                             float* __restrict__ gates, int R) {
    int i = threadIdx.x;
    if (i < R) {
        float x = gate_logits[i];
        gates[i] = 1.0f / (1.0f + expf(-x));
    }
}

// --- K2: scatter-add penalties + mark firing rules ---
__global__ void scatter_kernel(const int* __restrict__ rule_ids,
                               const int* __restrict__ token_ids,
                               const float* __restrict__ gates,
                               float* __restrict__ pen,
                               int* __restrict__ firing, int E) {
    int e = blockIdx.x * blockDim.x + threadIdx.x;
    if (e < E) {
        int r = rule_ids[e];
        int t = token_ids[e];
        atomicAdd(&pen[t], gates[r] * PENALTY_LAMBDA);
        firing[r] = 1;  // racy identical-value store: fine
    }
}

// --- K3: coverage loss reduction, one block of 512 ---
__global__ void loss_kernel(const float* __restrict__ gates,
                            const int* __restrict__ firing,
                            float* __restrict__ out_loss, int R) {
    __shared__ float s_gf[8];
    __shared__ float s_f[8];
    int i = threadIdx.x;  // blockDim.x == 512 == R
    float f  = (i < R && firing[i]) ? 1.0f : 0.0f;
    float gf = (f != 0.0f) ? gates[i] : 0.0f;
    // wave-64 butterfly
    for (int off = 32; off > 0; off >>= 1) {
        gf += __shfl_down(gf, off, 64);
        f  += __shfl_down(f,  off, 64);
    }
    int wave = i >> 6;          // 8 waves
    int lane = i & 63;
    if (lane == 0) { s_gf[wave] = gf; s_f[wave] = f; }
    __syncthreads();
    if (i == 0) {
        float tgf = 0.0f, tf = 0.0f;
        for (int w = 0; w < 8; ++w) { tgf += s_gf[w]; tf += s_f[w]; }
        float n = tf > 1.0f ? tf : 1.0f;
        *out_loss = -tgf / n;
    }
}

// --- K4: modified = logits - pen (float4), penalties = pen (scalar: region is
// only 4B-aligned because it starts at float offset B*V+1) ---
__global__ void broadcast_kernel(const float* __restrict__ logits,
                                 const float* __restrict__ pen,
                                 float* __restrict__ out_mod,
                                 float* __restrict__ out_pen, int V) {
    int v = (blockIdx.x * blockDim.x + threadIdx.x) * 4;
    int b = blockIdx.y;
    size_t base = (size_t)b * (size_t)V + (size_t)v;
    float4 p = *(const float4*)(pen + v);
    float4 l = *(const float4*)(logits + base);
    float4 m;
    m.x = l.x - p.x; m.y = l.y - p.y; m.z = l.z - p.z; m.w = l.w - p.w;
    *(float4*)(out_mod + base) = m;
    float* op = out_pen + base;   // unaligned-by-1-float region: scalar stores
    op[0] = p.x; op[1] = p.y; op[2] = p.z; op[3] = p.w;
}

extern "C" void kernel_launch(void* const* d_in, const int* in_sizes, int n_in,
                              void* d_out, int out_size, void* d_ws, size_t ws_size,
                              hipStream_t stream) {
    const float* logits      = (const float*)d_in[0];
    const float* gate_logits = (const float*)d_in[1];
    const int*   rule_ids    = (const int*)d_in[2];
    const int*   token_ids   = (const int*)d_in[3];
    float* out = (float*)d_out;

    const int R = in_sizes[1];          // 512
    const int E = in_sizes[2];          // 1,000,000
    const int V = 128000;
    const int B = in_sizes[0] / V;      // 64
    const size_t BV = (size_t)B * (size_t)V;

    // workspace layout: gates[R] | firing[R] | pen[V]
    float* gates  = (float*)d_ws;
    int*   firing = (int*)(gates + R);
    float* pen    = (float*)(firing + R);
    size_t ws_used = sizeof(float) * (size_t)(R + R + V);

    hipMemsetAsync(d_ws, 0, ws_used, stream);

    gates_kernel<<<1, R, 0, stream>>>(gate_logits, gates, R);

    scatter_kernel<<<(E + 255) / 256, 256, 0, stream>>>(
        rule_ids, token_ids, gates, pen, firing, E);

    loss_kernel<<<1, R, 0, stream>>>(gates, firing, out + BV, R);

    dim3 grid(V / (4 * 256), B);   // 125 x 64
    broadcast_kernel<<<grid, 256, 0, stream>>>(
        logits, pen, out, out + BV + 1, V);
}